// Round 4
// baseline (6057.832 us; speedup 1.0000x reference)
//
#include <hip/hip_runtime.h>

// LSTM forward, persistent-kernel, R4:
//   R3 post-mortem: direct-to-register H loads need ~160 VGPRs in flight but
//   only 92 were available (weights+acc in AGPRs) -> compiler serialized the
//   sc1 loads, exposing LLC latency ~8x/step. R4: keep flag barrier (R3 win),
//   return H to LDS but single-shot:
//   - all 128KB H staged via rotating regs (sc1 u64 loads -> ds_write_b128),
//     ONE latency exposure per step (one sync), no chunk pipeline.
//   - LDS = full H tile [64][1032 u16] (stride 2064B = 4 banks mod 32, 2-way
//     free). red[] aliases it (extra LDS-only sync orders the reuse).
//   - weights stay register(AGPR)-resident; x-frags prefetched across the
//     barrier and consumed while staging drains.

#define NB   128
#define SEQ  512
#define BATCH 64
#define DIM  256
#define HU   1024

typedef unsigned short u16;
typedef unsigned int   u32;
typedef unsigned long long u64;
typedef __attribute__((ext_vector_type(8))) short  short8;
typedef __attribute__((ext_vector_type(4))) float  f32x4;

__device__ __forceinline__ u16 f2bf(float x) {
  u32 u = __float_as_uint(x);
  u32 r = (u + 0x7FFFu + ((u >> 16) & 1u)) >> 16;   // RNE
  return (u16)r;
}
__device__ __forceinline__ float sigf(float x)  { return 1.0f / (1.0f + __expf(-x)); }
__device__ __forceinline__ float tanhfast(float x) { return 1.0f - 2.0f / (1.0f + __expf(2.0f * x)); }
__device__ __forceinline__ short8 cv8(uint4 v) {
  union { uint4 d; short8 s; } u; u.d = v; return u.s;
}

// ---------------- prologue kernels ----------------

__global__ void k_prep(const float* __restrict__ H0, u16* __restrict__ Hbuf0,
                       u32* __restrict__ flags) {
  int i = blockIdx.x * 256 + threadIdx.x;
  if (i < 2048) flags[i] = 0u;
  Hbuf0[i] = f2bf(H0[i]);   // i < 65536 == BATCH*HU
}

__global__ void k_xconv(const float* __restrict__ in, u16* __restrict__ out) {
  int i = blockIdx.x * 256 + threadIdx.x;
  float4 v = ((const float4*)in)[i];
  ushort4 o;
  o.x = f2bf(v.x); o.y = f2bf(v.y); o.z = f2bf(v.z); o.w = f2bf(v.w);
  ((ushort4*)out)[i] = o;
}

// Wpack[j][nt(2)][kc(40)][lane(64)][8] bf16 : MFMA B-fragment order.
__global__ void k_pack(const float* __restrict__ Wxi, const float* __restrict__ Whi,
                       const float* __restrict__ Wxf, const float* __restrict__ Whf,
                       const float* __restrict__ Wxo, const float* __restrict__ Who,
                       const float* __restrict__ Wxc, const float* __restrict__ Whc,
                       u16* __restrict__ Wpack) {
  int tid  = blockIdx.x * 256 + threadIdx.x;   // < 128*2*40*64 = 655360
  int lane = tid & 63;
  int kc   = (tid >> 6) % 40;
  int nt   = ((tid >> 6) / 40) & 1;
  int j    = (tid >> 6) / 80;
  int col  = nt * 16 + (lane & 15);
  int gate = col >> 3;
  int h    = j * 8 + (col & 7);
  const float* Wx = (gate == 0) ? Wxi : (gate == 1) ? Wxf : (gate == 2) ? Wxo : Wxc;
  const float* Wh = (gate == 0) ? Whi : (gate == 1) ? Whf : (gate == 2) ? Who : Whc;
  int kbase = kc * 32 + ((lane >> 4) << 3);
  u16 tmp[8];
#pragma unroll
  for (int e = 0; e < 8; e++) {
    int k = kbase + e;
    float v = (k < DIM) ? Wx[k * HU + h] : Wh[(k - DIM) * HU + h];
    tmp[e] = f2bf(v);
  }
  *(uint4*)(Wpack + (size_t)tid * 8) = *(uint4*)tmp;
}

// pred[b,t] = bd + sum_j part[t][j][b];  32768 threads
__global__ void k_predsum(const float* __restrict__ part, const float* __restrict__ bd,
                          float* __restrict__ pred) {
  int i = blockIdx.x * 256 + threadIdx.x;
  int b = i & 63, t = i >> 6;
  float s = bd[0];
  const float* p0 = part + (size_t)t * NB * 64 + b;
#pragma unroll 8
  for (int jj = 0; jj < NB; jj++) s += p0[jj * 64];
  pred[b * SEQ + t] = s;
}

// ---------------- main persistent kernel ----------------

struct MainParams {
  const u16* __restrict__ xbf;     // (B,S,D) bf16
  const u16* __restrict__ Wpack;   // [NB][2][40][64][8] bf16
  u16* __restrict__ Hbuf;          // [2][B][HU] bf16 (double buffer)
  const float* __restrict__ C0;
  const float* __restrict__ Wd;
  const float* __restrict__ bi;
  const float* __restrict__ bfg;
  const float* __restrict__ bo;
  const float* __restrict__ bc;
  float* __restrict__ ppart;       // [SEQ][NB][64] pred partials
  float* __restrict__ Hf;          // [B][HU]
  float* __restrict__ Cf;          // [B][HU]
  u32* __restrict__ flags;         // [NB] stride-16 u32
};

#define HROW 1032   // u16 row stride: 2064B = 516 banks = 4 mod 32 -> 2-way (free)

__global__ __launch_bounds__(256, 1) void lstm_main(MainParams p) {
  __shared__ u16 Hsm[64 * HROW];           // 132096 B; red[] aliases this
  float* red = (float*)Hsm;                // 34816 B used after MFMA phase

  const int tid  = threadIdx.x;
  const int wv   = tid >> 6, lane = tid & 63;
  const int j    = blockIdx.x;
  const int q8   = (lane >> 4) << 3;       // k sub-offset within a frag
  const int mrow = lane & 15;              // batch-row within 16-tile

  // resident weight B-fragments (compiler places in VGPR/AGPR):
  // x-chunks kc=2wv+s (s<2), H-chunks kc=8+8wv+s (s<8); nt in {0,1}
  short8 wx[2][2], wh[8][2];
  {
    const u16* base = p.Wpack + (size_t)j * 40960 + lane * 8;
#pragma unroll
    for (int s = 0; s < 2; s++)
#pragma unroll
      for (int nt = 0; nt < 2; nt++)
        wx[s][nt] = *(const short8*)(base + (nt * 40 + (2 * wv + s)) * 512);
#pragma unroll
    for (int s = 0; s < 8; s++)
#pragma unroll
      for (int nt = 0; nt < 2; nt++)
        wh[s][nt] = *(const short8*)(base + (nt * 40 + (8 + 8 * wv + s)) * 512);
  }

  // per-thread epilogue state
  const int b_  = tid >> 2, hq = tid & 3;
  const int hg0 = j * 8 + hq * 2, hg1 = hg0 + 1;
  float c0v = p.C0[b_ * HU + hg0], c1v = p.C0[b_ * HU + hg1];
  const float wd0 = p.Wd[hg0], wd1 = p.Wd[hg1];
  const float bi0 = p.bi[hg0],  bi1 = p.bi[hg1];
  const float bf0 = p.bfg[hg0], bf1 = p.bfg[hg1];
  const float bo0 = p.bo[hg0],  bo1 = p.bo[hg1];
  const float bc0 = p.bc[hg0],  bc1 = p.bc[hg1];
  float h0f = 0.f, h1f = 0.f;

  // x fragments for t=0 (prefetched across the barrier thereafter)
  uint4 ax[2][4];
#pragma unroll
  for (int s = 0; s < 2; s++)
#pragma unroll
    for (int mt = 0; mt < 4; mt++) {
      int m = mt * 16 + mrow;
      ax[s][mt] = *(const uint4*)(p.xbf + ((size_t)(m * SEQ + 0)) * DIM
                                  + (2 * wv + s) * 32 + q8);
    }

#pragma unroll 1
  for (int t = 0; t < SEQ; t++) {
    const int rb = t & 1;
    const u16* Hr = p.Hbuf + (size_t)rb * (BATCH * HU);
    u16*       Hw = p.Hbuf + (size_t)(rb ^ 1) * (BATCH * HU);

    // ---- stage ALL of H into LDS (sc1 loads -> ds_write), single shot ----
#pragma unroll
    for (int i = 0; i < 32; i++) {
      int g = tid + i * 256;                // uint4 index into H (8192 total)
      int row = g >> 7, c = g & 127;        // 128 uint4 per row
      const u64* s8 = (const u64*)(Hr + row * HU + c * 8);
      u64 lo = __hip_atomic_load(s8,     __ATOMIC_RELAXED, __HIP_MEMORY_SCOPE_AGENT);
      u64 hi = __hip_atomic_load(s8 + 1, __ATOMIC_RELAXED, __HIP_MEMORY_SCOPE_AGENT);
      uint4 v;
      v.x = (u32)lo; v.y = (u32)(lo >> 32); v.z = (u32)hi; v.w = (u32)(hi >> 32);
      *(uint4*)(&Hsm[row * HROW + c * 8]) = v;
    }

    // ---- x-phase MFMAs + next-step x prefetch (overlap staging drain) ----
    f32x4 acc[4][2];
#pragma unroll
    for (int mt = 0; mt < 4; mt++)
#pragma unroll
      for (int nt = 0; nt < 2; nt++) acc[mt][nt] = (f32x4){0.f, 0.f, 0.f, 0.f};
#pragma unroll
    for (int s = 0; s < 2; s++)
#pragma unroll
      for (int mt = 0; mt < 4; mt++) {
        short8 af = cv8(ax[s][mt]);
        acc[mt][0] = __builtin_amdgcn_mfma_f32_16x16x32_bf16(af, wx[s][0], acc[mt][0], 0, 0, 0);
        acc[mt][1] = __builtin_amdgcn_mfma_f32_16x16x32_bf16(af, wx[s][1], acc[mt][1], 0, 0, 0);
      }
    {
      const int tn = (t + 1 < SEQ) ? t + 1 : t;
#pragma unroll
      for (int s = 0; s < 2; s++)
#pragma unroll
        for (int mt = 0; mt < 4; mt++) {
          int m = mt * 16 + mrow;
          ax[s][mt] = *(const uint4*)(p.xbf + ((size_t)(m * SEQ + tn)) * DIM
                                      + (2 * wv + s) * 32 + q8);
        }
    }

    __syncthreads();   // staging (and x prefetch) complete

    // ---- H-phase MFMAs from LDS; wave wv covers kH in [256wv, 256wv+256) ----
#pragma unroll
    for (int s = 0; s < 8; s++)
#pragma unroll
      for (int mt = 0; mt < 4; mt++) {
        int m = mt * 16 + mrow;
        short8 af = *(const short8*)(&Hsm[m * HROW + 256 * wv + 32 * s + q8]);
        acc[mt][0] = __builtin_amdgcn_mfma_f32_16x16x32_bf16(af, wh[s][0], acc[mt][0], 0, 0, 0);
        acc[mt][1] = __builtin_amdgcn_mfma_f32_16x16x32_bf16(af, wh[s][1], acc[mt][1], 0, 0, 0);
      }

    __syncthreads();   // all H reads done before red[] overwrites Hsm

    // ---- K-split reduction: red[wv][col(32)][68] (aliases Hsm) ----
    {
      const int cb = lane & 15, q = lane >> 4;
#pragma unroll
      for (int mt = 0; mt < 4; mt++)
#pragma unroll
        for (int nt = 0; nt < 2; nt++) {
          int addr = (wv * 32 + nt * 16 + cb) * 68 + mt * 16 + q * 4;
          *(f32x4*)(red + addr) = acc[mt][nt];
        }
    }
    __syncthreads();

    // ---- epilogue ----
    float gv[8];
#pragma unroll
    for (int gg = 0; gg < 4; gg++)
#pragma unroll
      for (int e = 0; e < 2; e++) {
        int col = gg * 8 + hq * 2 + e;
        gv[gg * 2 + e] = red[(0 * 32 + col) * 68 + b_] + red[(1 * 32 + col) * 68 + b_]
                       + red[(2 * 32 + col) * 68 + b_] + red[(3 * 32 + col) * 68 + b_];
      }
    float i0 = sigf(gv[0] + bi0), i1 = sigf(gv[1] + bi1);
    float f0 = sigf(gv[2] + bf0), f1 = sigf(gv[3] + bf1);
    float o0 = sigf(gv[4] + bo0), o1 = sigf(gv[5] + bo1);
    float ct0 = tanhfast(gv[6] + bc0), ct1 = tanhfast(gv[7] + bc1);
    c0v = f0 * c0v + i0 * ct0;  c1v = f1 * c1v + i1 * ct1;
    h0f = o0 * tanhfast(c0v);   h1f = o1 * tanhfast(c1v);

    float pr = h0f * wd0 + h1f * wd1;
    pr += __shfl_xor(pr, 1);
    pr += __shfl_xor(pr, 2);
    if ((lane & 3) == 0) p.ppart[(size_t)t * NB * 64 + j * 64 + b_] = pr;

    // publish H_t (sc1 store to LLC)
    u32 hv = (u32)f2bf(h0f) | ((u32)f2bf(h1f) << 16);
    __hip_atomic_store((u32*)(Hw + b_ * HU + hg0), hv,
                       __ATOMIC_RELAXED, __HIP_MEMORY_SCOPE_AGENT);

    // ---- distributed flag barrier (syncthreads drains vmcnt first) ----
    __syncthreads();
    if (tid == 0)
      __hip_atomic_store(p.flags + j * 16, (u32)(t + 1),
                         __ATOMIC_RELAXED, __HIP_MEMORY_SCOPE_AGENT);
    if (tid < NB) {
      const u32* f = p.flags + tid * 16;
      while (__hip_atomic_load(f, __ATOMIC_RELAXED, __HIP_MEMORY_SCOPE_AGENT) < (u32)(t + 1))
        __builtin_amdgcn_s_sleep(1);
    }
    __syncthreads();
  }

  // finals
  p.Hf[b_ * HU + hg0] = h0f; p.Hf[b_ * HU + hg1] = h1f;
  p.Cf[b_ * HU + hg0] = c0v; p.Cf[b_ * HU + hg1] = c1v;
}

// ---------------- launch ----------------

extern "C" void kernel_launch(void* const* d_in, const int* in_sizes, int n_in,
                              void* d_out, int out_size, void* d_ws, size_t ws_size,
                              hipStream_t stream) {
  const float* inputs = (const float*)d_in[0];
  const float* H0  = (const float*)d_in[1];
  const float* C0  = (const float*)d_in[2];
  const float* Wxi = (const float*)d_in[3];
  const float* Whi = (const float*)d_in[4];
  const float* bi  = (const float*)d_in[5];
  const float* Wxf = (const float*)d_in[6];
  const float* Whf = (const float*)d_in[7];
  const float* bf_ = (const float*)d_in[8];
  const float* Wxo = (const float*)d_in[9];
  const float* Who = (const float*)d_in[10];
  const float* bo  = (const float*)d_in[11];
  const float* Wxc = (const float*)d_in[12];
  const float* Whc = (const float*)d_in[13];
  const float* bc  = (const float*)d_in[14];
  const float* Wd  = (const float*)d_in[15];
  const float* bd  = (const float*)d_in[16];

  char* ws = (char*)d_ws;
  u32*   flags = (u32*)ws;                                      // 8192 B
  u16*   Wpack = (u16*)(ws + 8192);                             // 10485760 B
  u16*   xbf   = (u16*)(ws + 8192 + 10485760);                  // 16777216 B
  u16*   Hbuf  = (u16*)(ws + 8192 + 10485760 + 16777216);       // 262144 B
  float* ppart = (float*)(ws + 8192 + 10485760 + 16777216 + 262144); // 16777216 B

  float* pred = (float*)d_out;
  float* Hf   = pred + BATCH * SEQ;
  float* Cf   = Hf + BATCH * HU;

  k_prep<<<256, 256, 0, stream>>>(H0, Hbuf, flags);
  k_xconv<<<8192, 256, 0, stream>>>(inputs, xbf);
  k_pack<<<2560, 256, 0, stream>>>(Wxi, Whi, Wxf, Whf, Wxo, Who, Wxc, Whc, Wpack);

  MainParams prm{xbf, Wpack, Hbuf, C0, Wd, bi, bf_, bo, bc, ppart, Hf, Cf, flags};
  lstm_main<<<dim3(NB), dim3(256), 0, stream>>>(prm);

  k_predsum<<<128, 256, 0, stream>>>(ppart, bd, pred);
}

// Round 5
// 2510.818 us; speedup vs baseline: 2.4127x; 2.4127x over previous
//
#include <hip/hip_runtime.h>

// LSTM forward, persistent-kernel, R5:
//   R4 post-mortem: single-shot staging serialized by VGPR budget -> LLC
//   latency exposed ~8-16x/step. R5: per-wave private staging via
//   global_load_lds (no VGPRs, all 32 issued back-to-back), per-wave manual
//   vmcnt flights (latency exposed ONCE), zero staging barriers:
//   - wave wv stages H cols [256wv,256wv+256) (32KB) with aux=17 (sc0|sc1,
//     LLC-coherent lds-DMA); consumes them itself -> no cross-wave sync.
//   - LDS: 4 x 33280B wave regions; 1KB blocks (2 rows x 512B) + 16B pad
//     -> ds_read_b128 2-way banks (free). red[] aliases own wave region.
//   - 3 syncthreads/step (red + 2 barrier); distributed flag barrier kept.

#define NB   128
#define SEQ  512
#define BATCH 64
#define DIM  256
#define HU   1024

typedef unsigned short u16;
typedef unsigned int   u32;
typedef unsigned long long u64;
typedef __attribute__((ext_vector_type(8))) short  short8;
typedef __attribute__((ext_vector_type(4))) float  f32x4;

typedef const __attribute__((address_space(1))) void* gptr_t;
typedef __attribute__((address_space(3))) void*       lptr_t;

// wait until <= N vector-memory ops outstanding (expcnt/lgkmcnt unconstrained)
#define WAITVM(N) __builtin_amdgcn_s_waitcnt(0x0F70 | ((N)&0xF) | (((N)>>4)<<14))

__device__ __forceinline__ u16 f2bf(float x) {
  u32 u = __float_as_uint(x);
  u32 r = (u + 0x7FFFu + ((u >> 16) & 1u)) >> 16;   // RNE
  return (u16)r;
}
__device__ __forceinline__ float sigf(float x)  { return 1.0f / (1.0f + __expf(-x)); }
__device__ __forceinline__ float tanhfast(float x) { return 1.0f - 2.0f / (1.0f + __expf(2.0f * x)); }
__device__ __forceinline__ short8 cv8(uint4 v) {
  union { uint4 d; short8 s; } u; u.d = v; return u.s;
}

// ---------------- prologue kernels ----------------

__global__ void k_prep(const float* __restrict__ H0, u16* __restrict__ Hbuf0,
                       u32* __restrict__ flags) {
  int i = blockIdx.x * 256 + threadIdx.x;
  if (i < 2048) flags[i] = 0u;
  Hbuf0[i] = f2bf(H0[i]);   // i < 65536 == BATCH*HU
}

__global__ void k_xconv(const float* __restrict__ in, u16* __restrict__ out) {
  int i = blockIdx.x * 256 + threadIdx.x;
  float4 v = ((const float4*)in)[i];
  ushort4 o;
  o.x = f2bf(v.x); o.y = f2bf(v.y); o.z = f2bf(v.z); o.w = f2bf(v.w);
  ((ushort4*)out)[i] = o;
}

// Wpack[j][nt(2)][kc(40)][lane(64)][8] bf16 : MFMA B-fragment order.
__global__ void k_pack(const float* __restrict__ Wxi, const float* __restrict__ Whi,
                       const float* __restrict__ Wxf, const float* __restrict__ Whf,
                       const float* __restrict__ Wxo, const float* __restrict__ Who,
                       const float* __restrict__ Wxc, const float* __restrict__ Whc,
                       u16* __restrict__ Wpack) {
  int tid  = blockIdx.x * 256 + threadIdx.x;   // < 128*2*40*64 = 655360
  int lane = tid & 63;
  int kc   = (tid >> 6) % 40;
  int nt   = ((tid >> 6) / 40) & 1;
  int j    = (tid >> 6) / 80;
  int col  = nt * 16 + (lane & 15);
  int gate = col >> 3;
  int h    = j * 8 + (col & 7);
  const float* Wx = (gate == 0) ? Wxi : (gate == 1) ? Wxf : (gate == 2) ? Wxo : Wxc;
  const float* Wh = (gate == 0) ? Whi : (gate == 1) ? Whf : (gate == 2) ? Who : Whc;
  int kbase = kc * 32 + ((lane >> 4) << 3);
  u16 tmp[8];
#pragma unroll
  for (int e = 0; e < 8; e++) {
    int k = kbase + e;
    float v = (k < DIM) ? Wx[k * HU + h] : Wh[(k - DIM) * HU + h];
    tmp[e] = f2bf(v);
  }
  *(uint4*)(Wpack + (size_t)tid * 8) = *(uint4*)tmp;
}

// pred[b,t] = bd + sum_j part[t][j][b];  32768 threads
__global__ void k_predsum(const float* __restrict__ part, const float* __restrict__ bd,
                          float* __restrict__ pred) {
  int i = blockIdx.x * 256 + threadIdx.x;
  int b = i & 63, t = i >> 6;
  float s = bd[0];
  const float* p0 = part + (size_t)t * NB * 64 + b;
#pragma unroll 8
  for (int jj = 0; jj < NB; jj++) s += p0[jj * 64];
  pred[b * SEQ + t] = s;
}

// ---------------- main persistent kernel ----------------

struct MainParams {
  const u16* __restrict__ xbf;     // (B,S,D) bf16
  const u16* __restrict__ Wpack;   // [NB][2][40][64][8] bf16
  u16* __restrict__ Hbuf;          // [2][B][HU] bf16 (double buffer)
  const float* __restrict__ C0;
  const float* __restrict__ Wd;
  const float* __restrict__ bi;
  const float* __restrict__ bfg;
  const float* __restrict__ bo;
  const float* __restrict__ bc;
  float* __restrict__ ppart;       // [SEQ][NB][64] pred partials
  float* __restrict__ Hf;          // [B][HU]
  float* __restrict__ Cf;          // [B][HU]
  u32* __restrict__ flags;         // [NB] stride-16 u32
};

// per-wave region: 32 blocks x (1024B + 16B pad) = 33280 B = 16640 u16
#define WVSZ 16640
#define BLKU 520     // u16 per 1KB block incl pad

__global__ __launch_bounds__(256, 1) void lstm_main(MainParams p) {
  __shared__ __align__(16) u16 Hsm[4 * WVSZ];   // 133120 B

  const int tid  = threadIdx.x;
  const int wv   = tid >> 6, lane = tid & 63;
  const int j    = blockIdx.x;
  const int q8   = (lane >> 4) << 3;       // k sub-offset within a frag
  const int mrow = lane & 15;              // batch-row within 16-tile
  const int l5   = lane >> 5, l31 = lane & 31;
  const int hcol0 = 256 * wv + l31 * 8;    // per-lane H column for staging

  const int wvb = wv * WVSZ;
  // per-lane ds_read base for MFMA A-frags (elements):
  const u16* Aw = Hsm + wvb + (mrow >> 1) * BLKU + (mrow & 1) * 256 + q8;
  float* redw = (float*)(Hsm + wvb);       // aliases own staging region

  // resident weight B-fragments: x-chunks kc=2wv+s (s<2), H kc=8+8wv+s (s<8)
  short8 wx[2][2], wh[8][2];
  {
    const u16* base = p.Wpack + (size_t)j * 40960 + lane * 8;
#pragma unroll
    for (int s = 0; s < 2; s++)
#pragma unroll
      for (int nt = 0; nt < 2; nt++)
        wx[s][nt] = *(const short8*)(base + (nt * 40 + (2 * wv + s)) * 512);
#pragma unroll
    for (int s = 0; s < 8; s++)
#pragma unroll
      for (int nt = 0; nt < 2; nt++)
        wh[s][nt] = *(const short8*)(base + (nt * 40 + (8 + 8 * wv + s)) * 512);
  }

  // per-thread epilogue state
  const int b_  = tid >> 2, hq = tid & 3;
  const int hg0 = j * 8 + hq * 2, hg1 = hg0 + 1;
  float c0v = p.C0[b_ * HU + hg0], c1v = p.C0[b_ * HU + hg1];
  const float wd0 = p.Wd[hg0], wd1 = p.Wd[hg1];
  const float bi0 = p.bi[hg0],  bi1 = p.bi[hg1];
  const float bf0 = p.bfg[hg0], bf1 = p.bfg[hg1];
  const float bo0 = p.bo[hg0],  bo1 = p.bo[hg1];
  const float bc0 = p.bc[hg0],  bc1 = p.bc[hg1];
  float h0f = 0.f, h1f = 0.f;

  // x fragments for t=0
  uint4 ax[2][4];
#pragma unroll
  for (int s = 0; s < 2; s++)
#pragma unroll
    for (int mt = 0; mt < 4; mt++) {
      int m = mt * 16 + mrow;
      ax[s][mt] = *(const uint4*)(p.xbf + ((size_t)(m * SEQ + 0)) * DIM
                                  + (2 * wv + s) * 32 + q8);
    }

#pragma unroll 1
  for (int t = 0; t < SEQ; t++) {
    const int rb = t & 1;
    const u16* Hr = p.Hbuf + (size_t)rb * (BATCH * HU);
    u16*       Hw = p.Hbuf + (size_t)(rb ^ 1) * (BATCH * HU);

    // ---- issue per-wave H staging: 32 global_load_lds (4 flights x 8) ----
    // instr i: rows {2i, 2i+1}, cols [256wv,256wv+256); lds = wvb + i*1040B,
    // per-lane deposit = base + lane*16 (HW). aux=17 = sc0|sc1 (LLC-coherent).
#pragma unroll
    for (int i = 0; i < 32; i++) {
      const u16* g = Hr + (size_t)((i << 1) + l5) * HU + hcol0;
      __builtin_amdgcn_global_load_lds((gptr_t)(const void*)g,
          (lptr_t)(void*)(Hsm + wvb + i * BLKU), 16, 0, 17);
      if ((i & 7) == 7) __builtin_amdgcn_sched_barrier(0);
    }
    __builtin_amdgcn_sched_barrier(0);

    // ---- x-phase MFMAs (ax resident) ----
    f32x4 acc[4][2];
#pragma unroll
    for (int mt = 0; mt < 4; mt++)
#pragma unroll
      for (int nt = 0; nt < 2; nt++) acc[mt][nt] = (f32x4){0.f, 0.f, 0.f, 0.f};
#pragma unroll
    for (int s = 0; s < 2; s++)
#pragma unroll
      for (int mt = 0; mt < 4; mt++) {
        short8 af = cv8(ax[s][mt]);
        acc[mt][0] = __builtin_amdgcn_mfma_f32_16x16x32_bf16(af, wx[s][0], acc[mt][0], 0, 0, 0);
        acc[mt][1] = __builtin_amdgcn_mfma_f32_16x16x32_bf16(af, wx[s][1], acc[mt][1], 0, 0, 0);
      }
    // ---- x prefetch for t+1 (8 plain loads; counted in WAITVM numbers) ----
    {
      const int tn = (t + 1 < SEQ) ? t + 1 : t;
#pragma unroll
      for (int s = 0; s < 2; s++)
#pragma unroll
        for (int mt = 0; mt < 4; mt++) {
          int m = mt * 16 + mrow;
          ax[s][mt] = *(const uint4*)(p.xbf + ((size_t)(m * SEQ + tn)) * DIM
                                      + (2 * wv + s) * 32 + q8);
        }
    }
    __builtin_amdgcn_sched_barrier(0);

    // ---- H-phase: flight mt = rows [16mt,16mt+16); outstanding = 32H + 8ax ----
#pragma unroll
    for (int mt = 0; mt < 4; mt++) {
      __builtin_amdgcn_sched_barrier(0);
      if (mt == 0)      WAITVM(32);   // oldest 8 H done
      else if (mt == 1) WAITVM(24);
      else if (mt == 2) WAITVM(16);
      else              WAITVM(8);    // all H done (8 ax still out)
      __builtin_amdgcn_sched_barrier(0);
#pragma unroll
      for (int s = 0; s < 8; s++) {
        short8 af = *(const short8*)(Aw + mt * (8 * BLKU) + s * 32);
        acc[mt][0] = __builtin_amdgcn_mfma_f32_16x16x32_bf16(af, wh[s][0], acc[mt][0], 0, 0, 0);
        acc[mt][1] = __builtin_amdgcn_mfma_f32_16x16x32_bf16(af, wh[s][1], acc[mt][1], 0, 0, 0);
      }
    }

    // ---- K-split reduction: redw[col(32)][68] in OWN wave region (alias ok:
    // only this wave read this region, program order ds_read -> ds_write) ----
    {
      const int cb = lane & 15, q = lane >> 4;
#pragma unroll
      for (int mt = 0; mt < 4; mt++)
#pragma unroll
        for (int nt = 0; nt < 2; nt++)
          *(f32x4*)(redw + (nt * 16 + cb) * 68 + mt * 16 + q * 4) = acc[mt][nt];
    }
    __syncthreads();

    // ---- epilogue ----
    float gv[8];
#pragma unroll
    for (int gg = 0; gg < 4; gg++)
#pragma unroll
      for (int e = 0; e < 2; e++) {
        int col = gg * 8 + hq * 2 + e;
        float s0 = ((const float*)(Hsm + 0 * WVSZ))[col * 68 + b_];
        float s1 = ((const float*)(Hsm + 1 * WVSZ))[col * 68 + b_];
        float s2 = ((const float*)(Hsm + 2 * WVSZ))[col * 68 + b_];
        float s3 = ((const float*)(Hsm + 3 * WVSZ))[col * 68 + b_];
        gv[gg * 2 + e] = (s0 + s1) + (s2 + s3);
      }
    float i0 = sigf(gv[0] + bi0), i1 = sigf(gv[1] + bi1);
    float f0 = sigf(gv[2] + bf0), f1 = sigf(gv[3] + bf1);
    float o0 = sigf(gv[4] + bo0), o1 = sigf(gv[5] + bo1);
    float ct0 = tanhfast(gv[6] + bc0), ct1 = tanhfast(gv[7] + bc1);
    c0v = f0 * c0v + i0 * ct0;  c1v = f1 * c1v + i1 * ct1;
    h0f = o0 * tanhfast(c0v);   h1f = o1 * tanhfast(c1v);

    float pr = h0f * wd0 + h1f * wd1;
    pr += __shfl_xor(pr, 1);
    pr += __shfl_xor(pr, 2);
    if ((lane & 3) == 0) p.ppart[(size_t)t * NB * 64 + j * 64 + b_] = pr;

    // publish H_t (sc1 store to LLC)
    u32 hv = (u32)f2bf(h0f) | ((u32)f2bf(h1f) << 16);
    __hip_atomic_store((u32*)(Hw + b_ * HU + hg0), hv,
                       __ATOMIC_RELAXED, __HIP_MEMORY_SCOPE_AGENT);

    // ---- distributed flag barrier (syncthreads drains vmcnt first) ----
    __syncthreads();
    if (tid == 0)
      __hip_atomic_store(p.flags + j * 16, (u32)(t + 1),
                         __ATOMIC_RELAXED, __HIP_MEMORY_SCOPE_AGENT);
    if (tid < NB) {
      const u32* f = p.flags + tid * 16;
      while (__hip_atomic_load(f, __ATOMIC_RELAXED, __HIP_MEMORY_SCOPE_AGENT) < (u32)(t + 1))
        __builtin_amdgcn_s_sleep(1);
    }
    __syncthreads();
  }

  // finals
  p.Hf[b_ * HU + hg0] = h0f; p.Hf[b_ * HU + hg1] = h1f;
  p.Cf[b_ * HU + hg0] = c0v; p.Cf[b_ * HU + hg1] = c1v;
}

// ---------------- launch ----------------

extern "C" void kernel_launch(void* const* d_in, const int* in_sizes, int n_in,
                              void* d_out, int out_size, void* d_ws, size_t ws_size,
                              hipStream_t stream) {
  const float* inputs = (const float*)d_in[0];
  const float* H0  = (const float*)d_in[1];
  const float* C0  = (const float*)d_in[2];
  const float* Wxi = (const float*)d_in[3];
  const float* Whi = (const float*)d_in[4];
  const float* bi  = (const float*)d_in[5];
  const float* Wxf = (const float*)d_in[6];
  const float* Whf = (const float*)d_in[7];
  const float* bf_ = (const float*)d_in[8];
  const float* Wxo = (const float*)d_in[9];
  const float* Who = (const float*)d_in[10];
  const float* bo  = (const float*)d_in[11];
  const float* Wxc = (const float*)d_in[12];
  const float* Whc = (const float*)d_in[13];
  const float* bc  = (const float*)d_in[14];
  const float* Wd  = (const float*)d_in[15];
  const float* bd  = (const float*)d_in[16];

  char* ws = (char*)d_ws;
  u32*   flags = (u32*)ws;                                      // 8192 B
  u16*   Wpack = (u16*)(ws + 8192);                             // 10485760 B
  u16*   xbf   = (u16*)(ws + 8192 + 10485760);                  // 16777216 B
  u16*   Hbuf  = (u16*)(ws + 8192 + 10485760 + 16777216);       // 262144 B
  float* ppart = (float*)(ws + 8192 + 10485760 + 16777216 + 262144); // 16777216 B

  float* pred = (float*)d_out;
  float* Hf   = pred + BATCH * SEQ;
  float* Cf   = Hf + BATCH * HU;

  k_prep<<<256, 256, 0, stream>>>(H0, Hbuf, flags);
  k_xconv<<<8192, 256, 0, stream>>>(inputs, xbf);
  k_pack<<<2560, 256, 0, stream>>>(Wxi, Whi, Wxf, Whf, Wxo, Who, Wxc, Whc, Wpack);

  MainParams prm{xbf, Wpack, Hbuf, C0, Wd, bi, bf_, bo, bc, ppart, Hf, Cf, flags};
  lstm_main<<<dim3(NB), dim3(256), 0, stream>>>(prm);

  k_predsum<<<128, 256, 0, stream>>>(ppart, bd, pred);
}

// Round 6
// 2337.795 us; speedup vs baseline: 2.5913x; 1.0740x over previous
//
#include <hip/hip_runtime.h>

// LSTM forward, persistent-kernel, R6:
//   R5 post-mortem: structure right (2.51ms), dominated by 16MB/step LLC
//   H-broadcast + K-split reduction + barrier. R6 re-tiles:
//   - grid 128 = 32 bj x 4 bb; block: M=16 rows (bb), N=128 gate cols (bj),
//     full K=1280  -> H-read/block 32KB, total 4MB/step (4x less broadcast).
//   - waves split N (2 n-tiles each, full K): NO K-reduction, gates finish
//     in accumulators; epilogue = one shfl_xor(8) + pointwise.
//   - weights 320 VGPR/wave (launch_bounds(256,1) -> 512 budget).
//   - staging: 8 global_load_lds/wave (aux=17), one syncthreads exposure;
//     LDS 33KB, row stride 2064B (2-way banks, free).
//   - flag barrier: reader polls only its 32 same-bb producers.

#define NB   128
#define SEQ  512
#define BATCH 64
#define DIM  256
#define HU   1024
#define ROWU 1032   // u16 row stride: 2064 B = 16 mod 128 -> b128 2-way (free)

typedef unsigned short u16;
typedef unsigned int   u32;
typedef unsigned long long u64;
typedef __attribute__((ext_vector_type(8))) short  short8;
typedef __attribute__((ext_vector_type(4))) float  f32x4;

typedef const __attribute__((address_space(1))) void* gptr_t;
typedef __attribute__((address_space(3))) void*       lptr_t;

__device__ __forceinline__ u16 f2bf(float x) {
  u32 u = __float_as_uint(x);
  u32 r = (u + 0x7FFFu + ((u >> 16) & 1u)) >> 16;   // RNE
  return (u16)r;
}
__device__ __forceinline__ float sigf(float x)  { return 1.0f / (1.0f + __expf(-x)); }
__device__ __forceinline__ float tanhfast(float x) { return 1.0f - 2.0f / (1.0f + __expf(2.0f * x)); }
__device__ __forceinline__ short8 cv8(uint4 v) {
  union { uint4 d; short8 s; } u; u.d = v; return u.s;
}

// ---------------- prologue kernels ----------------

__global__ void k_prep(const float* __restrict__ H0, u16* __restrict__ Hbuf0,
                       u32* __restrict__ flags) {
  int i = blockIdx.x * 256 + threadIdx.x;
  if (i < 2048) flags[i] = 0u;
  Hbuf0[i] = f2bf(H0[i]);   // i < 65536 == BATCH*HU
}

__global__ void k_xconv(const float* __restrict__ in, u16* __restrict__ out) {
  int i = blockIdx.x * 256 + threadIdx.x;
  float4 v = ((const float4*)in)[i];
  ushort4 o;
  o.x = f2bf(v.x); o.y = f2bf(v.y); o.z = f2bf(v.z); o.w = f2bf(v.w);
  ((ushort4*)out)[i] = o;
}

// Wpack[bj(32)][nt(8)][kc(40)][lane(64)][8] bf16 : MFMA B-fragment order.
// local col c = nt*16 + (lane&15) in [0,128):
//   h_high=c>>5, gate=(c>>3)&3, h_low=c&7, h = bj*32 + h_high*8 + h_low
__global__ void k_pack(const float* __restrict__ Wxi, const float* __restrict__ Whi,
                       const float* __restrict__ Wxf, const float* __restrict__ Whf,
                       const float* __restrict__ Wxo, const float* __restrict__ Who,
                       const float* __restrict__ Wxc, const float* __restrict__ Whc,
                       u16* __restrict__ Wpack) {
  int tid  = blockIdx.x * 256 + threadIdx.x;   // < 32*8*40*64 = 655360
  int lane = tid & 63;
  int kc   = (tid >> 6) % 40;
  int nt   = ((tid >> 6) / 40) & 7;
  int bj   = (tid >> 6) / 320;
  int c    = nt * 16 + (lane & 15);
  int gate = (c >> 3) & 3;
  int h    = bj * 32 + (c >> 5) * 8 + (c & 7);
  const float* Wx = (gate == 0) ? Wxi : (gate == 1) ? Wxf : (gate == 2) ? Wxo : Wxc;
  const float* Wh = (gate == 0) ? Whi : (gate == 1) ? Whf : (gate == 2) ? Who : Whc;
  int kbase = kc * 32 + ((lane >> 4) << 3);
  u16 tmp[8];
#pragma unroll
  for (int e = 0; e < 8; e++) {
    int k = kbase + e;
    float v = (k < DIM) ? Wx[k * HU + h] : Wh[(k - DIM) * HU + h];
    tmp[e] = f2bf(v);
  }
  *(uint4*)(Wpack + (size_t)tid * 8) = *(uint4*)tmp;
}

// pred[b,t] = bd + sum_{g<128} part[t*8192 + g*64 + b];  32768 threads
__global__ void k_predsum(const float* __restrict__ part, const float* __restrict__ bd,
                          float* __restrict__ pred) {
  int i = blockIdx.x * 256 + threadIdx.x;
  int b = i & 63, t = i >> 6;
  float s = bd[0];
  const float* p0 = part + (size_t)t * NB * 64 + b;
#pragma unroll 8
  for (int jj = 0; jj < NB; jj++) s += p0[jj * 64];
  pred[b * SEQ + t] = s;
}

// ---------------- main persistent kernel ----------------

struct MainParams {
  const u16* __restrict__ xbf;     // (B,S,D) bf16
  const u16* __restrict__ Wpack;   // [32][8][40][64][8] bf16
  u16* __restrict__ Hbuf;          // [2][B][HU] bf16 (double buffer)
  const float* __restrict__ C0;
  const float* __restrict__ Wd;
  const float* __restrict__ bi;
  const float* __restrict__ bfg;
  const float* __restrict__ bo;
  const float* __restrict__ bc;
  float* __restrict__ ppart;       // [SEQ][32bj][4wv][64b] pred partials
  float* __restrict__ Hf;          // [B][HU]
  float* __restrict__ Cf;          // [B][HU]
  u32* __restrict__ flags;         // [4bb][32bj] stride-16 u32
};

__global__ __launch_bounds__(256, 1) void lstm_main(MainParams p) {
  __shared__ __align__(16) u16 Hsm[16 * ROWU];   // 33024 B

  const int tid  = threadIdx.x;
  const int wv   = tid >> 6, lane = tid & 63;
  const int bj   = blockIdx.x >> 2, bb = blockIdx.x & 3;
  const int q    = lane >> 4;              // row quad
  const int q8   = q * 8;                  // k sub-offset in frag
  const int m16  = lane & 15;
  const int hl   = lane & 7;
  const bool hiH = (lane & 8) != 0;        // f/c-holder half

  const int hglob = bj * 32 + wv * 8 + hl; // this thread's h column
  const int row0  = 16 * bb;               // block's first batch row

  // resident weight B-fragments: wave wv owns n-tiles {2wv, 2wv+1}, full K.
  short8 wx[8][2], wh[32][2];
  {
    const u16* wbase = p.Wpack + ((size_t)bj * 8 + 2 * wv) * (40 * 512) + lane * 8;
#pragma unroll
    for (int kc = 0; kc < 8; kc++)
#pragma unroll
      for (int ntl = 0; ntl < 2; ntl++)
        wx[kc][ntl] = *(const short8*)(wbase + ((size_t)ntl * 40 + kc) * 512);
#pragma unroll
    for (int kc = 0; kc < 32; kc++)
#pragma unroll
      for (int ntl = 0; ntl < 2; ntl++)
        wh[kc][ntl] = *(const short8*)(wbase + ((size_t)ntl * 40 + 8 + kc) * 512);
  }

  // per-thread epilogue state: 4 rows (q*4+r), one h
  const float bI = p.bi[hglob],  bF = p.bfg[hglob];
  const float bO = p.bo[hglob],  bC = p.bc[hglob];
  const float wdv = p.Wd[hglob];
  float Cst[4], Hst[4];
#pragma unroll
  for (int r = 0; r < 4; r++) {
    Cst[r] = p.C0[(row0 + q * 4 + r) * HU + hglob];
    Hst[r] = 0.f;
  }

  // LDS read base for A-frags (m = lane&15 -> local row)
  const u16* Aw = Hsm + m16 * ROWU + q8;

  // x fragments for t=0: row = row0 + m16, k = kc*32 + q8
  uint4 ax[8];
#pragma unroll
  for (int kc = 0; kc < 8; kc++)
    ax[kc] = *(const uint4*)(p.xbf + ((size_t)((row0 + m16) * SEQ + 0)) * DIM
                             + kc * 32 + q8);

#pragma unroll 1
  for (int t = 0; t < SEQ; t++) {
    const int rb = t & 1;
    const u16* Hr = p.Hbuf + (size_t)rb * (BATCH * HU);
    u16*       Hw = p.Hbuf + (size_t)(rb ^ 1) * (BATCH * HU);

    // ---- issue H staging: wave wv -> segments [8wv, 8wv+8) of 32 ----
    // segment s: row = s>>1, cols [(s&1)*512, +512); aux=17 (LLC-coherent DMA)
#pragma unroll
    for (int i = 0; i < 8; i++) {
      int s = wv * 8 + i, row = s >> 1, half = s & 1;
      const u16* g = Hr + (size_t)(row0 + row) * HU + half * 512 + lane * 8;
      __builtin_amdgcn_global_load_lds((gptr_t)(const void*)g,
          (lptr_t)(void*)(Hsm + row * ROWU + half * 512), 16, 0, 17);
    }

    // ---- x-phase MFMAs (in the shadow of DMA latency) ----
    f32x4 acc[2][4];
#pragma unroll
    for (int ntl = 0; ntl < 2; ntl++)
#pragma unroll
      for (int c = 0; c < 4; c++) acc[ntl][c] = (f32x4){0.f, 0.f, 0.f, 0.f};
#pragma unroll
    for (int kc = 0; kc < 8; kc++) {
      short8 af = cv8(ax[kc]);
      acc[0][kc & 3] = __builtin_amdgcn_mfma_f32_16x16x32_bf16(af, wx[kc][0], acc[0][kc & 3], 0, 0, 0);
      acc[1][kc & 3] = __builtin_amdgcn_mfma_f32_16x16x32_bf16(af, wx[kc][1], acc[1][kc & 3], 0, 0, 0);
    }

    __syncthreads();   // drains DMA (vmcnt0) + barrier: Hsm complete

    // ---- x prefetch for t+1 (completes during H phase / next flag wait) ----
    {
      const int tn = (t + 1 < SEQ) ? t + 1 : t;
#pragma unroll
      for (int kc = 0; kc < 8; kc++)
        ax[kc] = *(const uint4*)(p.xbf + ((size_t)((row0 + m16) * SEQ + tn)) * DIM
                                 + kc * 32 + q8);
    }

    // ---- H-phase MFMAs from LDS (full K per wave, 2 n-tiles) ----
#pragma unroll
    for (int kc = 0; kc < 32; kc++) {
      short8 af = *(const short8*)(Aw + kc * 32);
      acc[0][kc & 3] = __builtin_amdgcn_mfma_f32_16x16x32_bf16(af, wh[kc][0], acc[0][kc & 3], 0, 0, 0);
      acc[1][kc & 3] = __builtin_amdgcn_mfma_f32_16x16x32_bf16(af, wh[kc][1], acc[1][kc & 3], 0, 0, 0);
    }

    // ---- gate combine: ntl=0 -> {i,f}, ntl=1 -> {o,c}; swap via shfl_xor(8) ----
    f32x4 g01 = (acc[0][0] + acc[0][1]) + (acc[0][2] + acc[0][3]);
    f32x4 g23 = (acc[1][0] + acc[1][1]) + (acc[1][2] + acc[1][3]);

    float pr[4];
#pragma unroll
    for (int r = 0; r < 4; r++) {
      float u0 = g01[r], u1 = g23[r];
      float v0 = __shfl_xor(u0, 8);
      float v1 = __shfl_xor(u1, 8);
      float gi = hiH ? v0 : u0, gf = hiH ? u0 : v0;
      float go = hiH ? v1 : u1, gc = hiH ? u1 : v1;
      float iv = sigf(gi + bI), fv = sigf(gf + bF);
      float ov = sigf(go + bO), ct = tanhfast(gc + bC);
      Cst[r] = fv * Cst[r] + iv * ct;
      Hst[r] = ov * tanhfast(Cst[r]);
      pr[r]  = Hst[r] * wdv;
    }

    // publish H_t (bit3==0 lanes; 2B sc1 stores, rows q*4+r)
    if (!hiH) {
#pragma unroll
      for (int r = 0; r < 4; r++)
        __hip_atomic_store(Hw + (size_t)(row0 + q * 4 + r) * HU + hglob,
                           f2bf(Hst[r]), __ATOMIC_RELAXED, __HIP_MEMORY_SCOPE_AGENT);
    }

    // pred partials: reduce over 8 h (both halves redundantly), store 4 rows
#pragma unroll
    for (int r = 0; r < 4; r++) {
      pr[r] += __shfl_xor(pr[r], 1);
      pr[r] += __shfl_xor(pr[r], 2);
      pr[r] += __shfl_xor(pr[r], 4);
    }
    if (m16 == 0) {
      float4 st = {pr[0], pr[1], pr[2], pr[3]};
      *(float4*)(p.ppart + (((size_t)t * 32 + bj) * 4 + wv) * 64 + row0 + q * 4) = st;
    }

    // ---- distributed flag barrier: only the 32 same-bb producers ----
    __syncthreads();   // drains vmcnt -> H stores at LLC before flag
    if (tid == 0)
      __hip_atomic_store(p.flags + (bb * 32 + bj) * 16, (u32)(t + 1),
                         __ATOMIC_RELAXED, __HIP_MEMORY_SCOPE_AGENT);
    if (tid < 32) {
      const u32* f = p.flags + (bb * 32 + tid) * 16;
      while (__hip_atomic_load(f, __ATOMIC_RELAXED, __HIP_MEMORY_SCOPE_AGENT) < (u32)(t + 1))
        __builtin_amdgcn_s_sleep(1);
    }
    __syncthreads();
  }

  // finals
  if (!hiH) {
#pragma unroll
    for (int r = 0; r < 4; r++) {
      int row = row0 + q * 4 + r;
      p.Hf[row * HU + hglob] = Hst[r];
      p.Cf[row * HU + hglob] = Cst[r];
    }
  }
}

// ---------------- launch ----------------

extern "C" void kernel_launch(void* const* d_in, const int* in_sizes, int n_in,
                              void* d_out, int out_size, void* d_ws, size_t ws_size,
                              hipStream_t stream) {
  const float* inputs = (const float*)d_in[0];
  const float* H0  = (const float*)d_in[1];
  const float* C0  = (const float*)d_in[2];
  const float* Wxi = (const float*)d_in[3];
  const float* Whi = (const float*)d_in[4];
  const float* bi  = (const float*)d_in[5];
  const float* Wxf = (const float*)d_in[6];
  const float* Whf = (const float*)d_in[7];
  const float* bf_ = (const float*)d_in[8];
  const float* Wxo = (const float*)d_in[9];
  const float* Who = (const float*)d_in[10];
  const float* bo  = (const float*)d_in[11];
  const float* Wxc = (const float*)d_in[12];
  const float* Whc = (const float*)d_in[13];
  const float* bc  = (const float*)d_in[14];
  const float* Wd  = (const float*)d_in[15];
  const float* bd  = (const float*)d_in[16];

  char* ws = (char*)d_ws;
  u32*   flags = (u32*)ws;                                      // 8192 B
  u16*   Wpack = (u16*)(ws + 8192);                             // 10485760 B
  u16*   xbf   = (u16*)(ws + 8192 + 10485760);                  // 16777216 B
  u16*   Hbuf  = (u16*)(ws + 8192 + 10485760 + 16777216);       // 262144 B
  float* ppart = (float*)(ws + 8192 + 10485760 + 16777216 + 262144); // 16777216 B

  float* pred = (float*)d_out;
  float* Hf   = pred + BATCH * SEQ;
  float* Cf   = Hf + BATCH * HU;

  k_prep<<<256, 256, 0, stream>>>(H0, Hbuf, flags);
  k_xconv<<<8192, 256, 0, stream>>>(inputs, xbf);
  k_pack<<<2560, 256, 0, stream>>>(Wxi, Whi, Wxf, Whf, Wxo, Who, Wxc, Whc, Wpack);

  MainParams prm{xbf, Wpack, Hbuf, C0, Wd, bi, bf_, bo, bc, ppart, Hf, Cf, flags};
  lstm_main<<<dim3(NB), dim3(256), 0, stream>>>(prm);

  k_predsum<<<128, 256, 0, stream>>>(ppart, bd, pred);
}